// Round 1
// baseline (142.927 us; speedup 1.0000x reference)
//
#include <hip/hip_runtime.h>
#include <hip/hip_bf16.h>
#include <cstdint>

typedef unsigned short u16;
typedef __bf16 bf16x8 __attribute__((ext_vector_type(8)));
typedef u16 u16x8 __attribute__((ext_vector_type(8)));
typedef float f32x4 __attribute__((ext_vector_type(4)));

#define B_ 2
#define S_ 2048
#define H_ 16
#define HS_ 64
#define EMB_ 1024

static __device__ __forceinline__ u16 f2bf(float f) {
  unsigned int u = __float_as_uint(f);
  u += 0x7fffu + ((u >> 16) & 1u);   // RNE
  return (u16)(u >> 16);
}

static __device__ __forceinline__ f32x4 mfma16(u16x8 a, u16x8 b, f32x4 c) {
  return __builtin_amdgcn_mfma_f32_16x16x32_bf16(
      __builtin_bit_cast(bf16x8, a), __builtin_bit_cast(bf16x8, b), c, 0, 0, 0);
}

// ---------------- K0: Wo[k][n] fp32 -> Wot[n][k] bf16 ----------------
__global__ __launch_bounds__(256) void k_transpose_wo(const float* __restrict__ Wo,
                                                      u16* __restrict__ Wot) {
  __shared__ __align__(16) u16 T[64][72];
  const int kb = blockIdx.y * 64, nb = blockIdx.x * 64;
  const int r = threadIdx.x >> 2;          // 0..63
  const int c0 = (threadIdx.x & 3) << 4;   // 0,16,32,48
  const float* src = Wo + (size_t)(kb + r) * EMB_ + nb + c0;
#pragma unroll
  for (int i = 0; i < 16; i += 4) {
    float4 f = *(const float4*)(src + i);
    T[c0 + i + 0][r] = f2bf(f.x);
    T[c0 + i + 1][r] = f2bf(f.y);
    T[c0 + i + 2][r] = f2bf(f.z);
    T[c0 + i + 3][r] = f2bf(f.w);
  }
  __syncthreads();
  u16* dst = Wot + (size_t)(nb + r) * EMB_ + kb + c0;
  *(u16x8*)(dst)     = *(const u16x8*)&T[r][c0];
  *(u16x8*)(dst + 8) = *(const u16x8*)&T[r][c0 + 8];
}

// ---------------- K1: per-head projections ----------------
// Qo,Ko: [bh][s][64] bf16 row-major; Vt: [bh][e][s] bf16 (transposed)
__global__ __launch_bounds__(256) void k_proj(
    const float* __restrict__ xq, const float* __restrict__ xk, const float* __restrict__ xv,
    const float* __restrict__ Wq, const float* __restrict__ Wk, const float* __restrict__ Wv,
    u16* __restrict__ Qo, u16* __restrict__ Ko, u16* __restrict__ Vt) {
  __shared__ __align__(16) u16 X[3][64][64];
  __shared__ __align__(16) u16 WT[3][64][64];  // WT[t][e][d] = W[t][d][e]
  const int sb = blockIdx.x;   // s-block 0..31
  const int bh = blockIdx.y;   // 0..31
  const int b = bh >> 4;
  const int h = bh & 15;
  const int t = threadIdx.x;
  const int r = t >> 2;           // 0..63
  const int c0 = (t & 3) << 4;    // 0,16,32,48
  const float* xs[3] = {xq, xk, xv};
  const float* wsrc[3] = {Wq, Wk, Wv};
#pragma unroll
  for (int tn = 0; tn < 3; ++tn) {
    const float* src = xs[tn] + ((size_t)(b * S_ + sb * 64 + r)) * HS_ + c0;
#pragma unroll
    for (int i = 0; i < 16; i += 8) {
      float4 fa = *(const float4*)(src + i);
      float4 fb = *(const float4*)(src + i + 4);
      u16x8 v = {f2bf(fa.x), f2bf(fa.y), f2bf(fa.z), f2bf(fa.w),
                 f2bf(fb.x), f2bf(fb.y), f2bf(fb.z), f2bf(fb.w)};
      *(u16x8*)&X[tn][r][c0 + i] = v;
    }
    const float* wsp = wsrc[tn] + ((size_t)(h * HS_ + r)) * HS_ + c0;  // W[h][d=r][e]
#pragma unroll
    for (int i = 0; i < 16; i += 4) {
      float4 f = *(const float4*)(wsp + i);
      WT[tn][c0 + i + 0][r] = f2bf(f.x);
      WT[tn][c0 + i + 1][r] = f2bf(f.y);
      WT[tn][c0 + i + 2][r] = f2bf(f.z);
      WT[tn][c0 + i + 3][r] = f2bf(f.w);
    }
  }
  __syncthreads();
  const int lane = t & 63, wv = t >> 6;
  const int lq = lane & 15, lg = lane >> 4;
  // Q, K : D[s][e]
#pragma unroll
  for (int tn = 0; tn < 2; ++tn) {
    u16x8 a0 = *(const u16x8*)&X[tn][wv * 16 + lq][lg * 8];
    u16x8 a1 = *(const u16x8*)&X[tn][wv * 16 + lq][32 + lg * 8];
    u16* outp = (tn == 0) ? Qo : Ko;
#pragma unroll
    for (int et = 0; et < 4; ++et) {
      u16x8 b0 = *(const u16x8*)&WT[tn][et * 16 + lq][lg * 8];
      u16x8 b1 = *(const u16x8*)&WT[tn][et * 16 + lq][32 + lg * 8];
      f32x4 acc = {0.f, 0.f, 0.f, 0.f};
      acc = mfma16(a0, b0, acc);
      acc = mfma16(a1, b1, acc);
#pragma unroll
      for (int rr = 0; rr < 4; ++rr) {
        int s = sb * 64 + wv * 16 + lg * 4 + rr;
        outp[((size_t)(bh * S_ + s)) * HS_ + et * 16 + lq] = f2bf(acc[rr]);
      }
    }
  }
  // V : D[e][s] = sum_d WT[e][d] * X[s][d]  -> write transposed Vt
  u16x8 xb0 = *(const u16x8*)&X[2][wv * 16 + lq][lg * 8];
  u16x8 xb1 = *(const u16x8*)&X[2][wv * 16 + lq][32 + lg * 8];
#pragma unroll
  for (int et = 0; et < 4; ++et) {
    u16x8 a0 = *(const u16x8*)&WT[2][et * 16 + lq][lg * 8];
    u16x8 a1 = *(const u16x8*)&WT[2][et * 16 + lq][32 + lg * 8];
    f32x4 acc = {0.f, 0.f, 0.f, 0.f};
    acc = mfma16(a0, xb0, acc);
    acc = mfma16(a1, xb1, acc);
#pragma unroll
    for (int rr = 0; rr < 4; ++rr) {
      int e = et * 16 + lg * 4 + rr;
      int s = sb * 64 + wv * 16 + lq;
      Vt[((size_t)(bh * HS_ + e)) * S_ + s] = f2bf(acc[rr]);
    }
  }
}

// ---------------- K2: causal flash attention ----------------
// Co (concat): [b][s][h*64+e] bf16
__global__ __launch_bounds__(256) void k_attn(
    const u16* __restrict__ Q, const u16* __restrict__ K, const u16* __restrict__ Vt,
    u16* __restrict__ Co) {
  __shared__ __align__(16) u16 Ks[64][64];      // K[kv][d]
  __shared__ __align__(16) u16 Vs[64][64];      // Vt[e][kv]
  __shared__ __align__(16) u16 Ps[4][16][72];   // per-wave P[q][kv] (padded)
  const int pair = blockIdx.x;  // 0..15 -> handles qb=pair and qb=31-pair
  const int bh = blockIdx.y;    // 0..31
  const int b = bh >> 4, h = bh & 15;
  const int t = threadIdx.x;
  const int lane = t & 63, wv = t >> 6;
  const int lq = lane & 15, lg = lane >> 4;
  const int sr = t >> 2;           // staging row 0..63
  const int sc0 = (t & 3) << 4;    // staging col 0,16,32,48
  const float inv_scale = 0.022097086912079608f;  // 1/sqrt(2048)
  const float NEG_BIG = -1e30f;

  for (int halfi = 0; halfi < 2; ++halfi) {
    const int qb = (halfi == 0) ? pair : 31 - pair;
    const int q0 = qb * 64 + wv * 16;
    const u16* Qb = Q + (size_t)bh * S_ * HS_;
    u16x8 qa0 = *(const u16x8*)&Qb[(size_t)(q0 + lq) * HS_ + lg * 8];
    u16x8 qa1 = *(const u16x8*)&Qb[(size_t)(q0 + lq) * HS_ + 32 + lg * 8];
    f32x4 o[4];
#pragma unroll
    for (int et = 0; et < 4; ++et) { f32x4 z = {0.f,0.f,0.f,0.f}; o[et] = z; }
    float m[4] = {NEG_BIG, NEG_BIG, NEG_BIG, NEG_BIG};
    float ll[4] = {0.f, 0.f, 0.f, 0.f};

    for (int j = 0; j <= qb; ++j) {
      __syncthreads();
      {
        const u16* ksrc = K + ((size_t)(bh * S_ + j * 64 + sr)) * HS_ + sc0;
        *(u16x8*)&Ks[sr][sc0]     = *(const u16x8*)(ksrc);
        *(u16x8*)&Ks[sr][sc0 + 8] = *(const u16x8*)(ksrc + 8);
        const u16* vsrc = Vt + ((size_t)(bh * HS_ + sr)) * S_ + j * 64 + sc0;
        *(u16x8*)&Vs[sr][sc0]     = *(const u16x8*)(vsrc);
        *(u16x8*)&Vs[sr][sc0 + 8] = *(const u16x8*)(vsrc + 8);
      }
      __syncthreads();
      // QK^T: D[q][kv], 4 kv-subtiles of 16
      float sv[4][4];
#pragma unroll
      for (int c = 0; c < 4; ++c) {
        u16x8 kb0 = *(const u16x8*)&Ks[c * 16 + lq][lg * 8];
        u16x8 kb1 = *(const u16x8*)&Ks[c * 16 + lq][32 + lg * 8];
        f32x4 acc = {0.f, 0.f, 0.f, 0.f};
        acc = mfma16(qa0, kb0, acc);
        acc = mfma16(qa1, kb1, acc);
#pragma unroll
        for (int rr = 0; rr < 4; ++rr) sv[c][rr] = acc[rr] * inv_scale;
      }
      if (j == qb) {  // diagonal tile: causal mask (local compare valid)
#pragma unroll
        for (int c = 0; c < 4; ++c)
#pragma unroll
          for (int rr = 0; rr < 4; ++rr) {
            int kv = c * 16 + lq;
            int qq = wv * 16 + lg * 4 + rr;
            if (kv > qq) sv[c][rr] = NEG_BIG;
          }
      }
      // online softmax (rows q = lg*4+rr; reduce over kv = lanes 0..15 of group)
      float scale_r[4];
#pragma unroll
      for (int rr = 0; rr < 4; ++rr) {
        float mx = fmaxf(fmaxf(sv[0][rr], sv[1][rr]), fmaxf(sv[2][rr], sv[3][rr]));
#pragma unroll
        for (int msk = 1; msk < 16; msk <<= 1) mx = fmaxf(mx, __shfl_xor(mx, msk, 64));
        float mn = fmaxf(m[rr], mx);
        float scl = __expf(m[rr] - mn);
        float ps = 0.f;
#pragma unroll
        for (int c = 0; c < 4; ++c) {
          float p = __expf(sv[c][rr] - mn);
          sv[c][rr] = p;
          ps += p;
        }
#pragma unroll
        for (int msk = 1; msk < 16; msk <<= 1) ps += __shfl_xor(ps, msk, 64);
        ll[rr] = ll[rr] * scl + ps;
        m[rr] = mn;
        scale_r[rr] = scl;
      }
      // P -> LDS (bf16), per-wave private region
#pragma unroll
      for (int c = 0; c < 4; ++c)
#pragma unroll
        for (int rr = 0; rr < 4; ++rr)
          Ps[wv][lg * 4 + rr][c * 16 + lq] = f2bf(sv[c][rr]);
      // rescale O
#pragma unroll
      for (int et = 0; et < 4; ++et)
#pragma unroll
        for (int rr = 0; rr < 4; ++rr) o[et][rr] *= scale_r[rr];
      // PV: O[q][e] += P[q][kv] * V[kv][e]
      u16x8 pa0 = *(const u16x8*)&Ps[wv][lq][lg * 8];
      u16x8 pa1 = *(const u16x8*)&Ps[wv][lq][32 + lg * 8];
#pragma unroll
      for (int et = 0; et < 4; ++et) {
        u16x8 vb0 = *(const u16x8*)&Vs[et * 16 + lq][lg * 8];
        u16x8 vb1 = *(const u16x8*)&Vs[et * 16 + lq][32 + lg * 8];
        o[et] = mfma16(pa0, vb0, o[et]);
        o[et] = mfma16(pa1, vb1, o[et]);
      }
    }
    // epilogue: O /= l, write concat
#pragma unroll
    for (int rr = 0; rr < 4; ++rr) {
      float inv = 1.0f / ll[rr];
      int qg = qb * 64 + wv * 16 + lg * 4 + rr;
      u16* dst = Co + ((size_t)(b * S_ + qg)) * EMB_ + h * HS_;
#pragma unroll
      for (int et = 0; et < 4; ++et)
        dst[et * 16 + lq] = f2bf(o[et][rr] * inv);
    }
  }
}

// ---------------- K3: out = concat @ Wo + bo (fp32 out) ----------------
__global__ __launch_bounds__(256) void k_outproj(
    const u16* __restrict__ Cc, const u16* __restrict__ Wot,
    const float* __restrict__ bo, float* __restrict__ out) {
  __shared__ __align__(16) u16 As[128][64];
  __shared__ __align__(16) u16 Bs[128][64];
  const int nb = blockIdx.x;  // 0..7
  const int mb = blockIdx.y;  // 0..31
  const int t = threadIdx.x;
  const int lane = t & 63, wv = t >> 6;
  const int lq = lane & 15, lg = lane >> 4;
  const int wr = wv >> 1, wc = wv & 1;
  const int sr = t >> 1;           // 0..127
  const int sc0 = (t & 1) << 5;    // 0,32
  f32x4 acc[4][4];
#pragma unroll
  for (int mi = 0; mi < 4; ++mi)
#pragma unroll
    for (int ni = 0; ni < 4; ++ni) { f32x4 z = {0.f,0.f,0.f,0.f}; acc[mi][ni] = z; }
  for (int kt = 0; kt < 16; ++kt) {
    __syncthreads();
    const u16* asrc = Cc + ((size_t)(mb * 128 + sr)) * EMB_ + kt * 64 + sc0;
    *(u16x8*)&As[sr][sc0]      = *(const u16x8*)(asrc);
    *(u16x8*)&As[sr][sc0 + 8]  = *(const u16x8*)(asrc + 8);
    *(u16x8*)&As[sr][sc0 + 16] = *(const u16x8*)(asrc + 16);
    *(u16x8*)&As[sr][sc0 + 24] = *(const u16x8*)(asrc + 24);
    const u16* bsrc = Wot + ((size_t)(nb * 128 + sr)) * EMB_ + kt * 64 + sc0;
    *(u16x8*)&Bs[sr][sc0]      = *(const u16x8*)(bsrc);
    *(u16x8*)&Bs[sr][sc0 + 8]  = *(const u16x8*)(bsrc + 8);
    *(u16x8*)&Bs[sr][sc0 + 16] = *(const u16x8*)(bsrc + 16);
    *(u16x8*)&Bs[sr][sc0 + 24] = *(const u16x8*)(bsrc + 24);
    __syncthreads();
#pragma unroll
    for (int kf = 0; kf < 2; ++kf) {
      u16x8 af[4], bf[4];
#pragma unroll
      for (int mi = 0; mi < 4; ++mi)
        af[mi] = *(const u16x8*)&As[wr * 64 + mi * 16 + lq][kf * 32 + lg * 8];
#pragma unroll
      for (int ni = 0; ni < 4; ++ni)
        bf[ni] = *(const u16x8*)&Bs[wc * 64 + ni * 16 + lq][kf * 32 + lg * 8];
#pragma unroll
      for (int mi = 0; mi < 4; ++mi)
#pragma unroll
        for (int ni = 0; ni < 4; ++ni)
          acc[mi][ni] = mfma16(af[mi], bf[ni], acc[mi][ni]);
    }
  }
#pragma unroll
  for (int mi = 0; mi < 4; ++mi) {
#pragma unroll
    for (int ni = 0; ni < 4; ++ni) {
      int col = nb * 128 + wc * 64 + ni * 16 + lq;
      float bv = bo[col];
#pragma unroll
      for (int rr = 0; rr < 4; ++rr) {
        int row = mb * 128 + wr * 64 + mi * 16 + lg * 4 + rr;
        out[(size_t)row * EMB_ + col] = acc[mi][ni][rr] + bv;
      }
    }
  }
}

extern "C" void kernel_launch(void* const* d_in, const int* in_sizes, int n_in,
                              void* d_out, int out_size, void* d_ws, size_t ws_size,
                              hipStream_t stream) {
  const float* xk = (const float*)d_in[0];
  const float* xv = (const float*)d_in[1];
  const float* xq = (const float*)d_in[2];
  const float* Wk = (const float*)d_in[3];
  const float* Wv = (const float*)d_in[4];
  const float* Wq = (const float*)d_in[5];
  const float* Wo = (const float*)d_in[6];
  const float* bo = (const float*)d_in[7];
  float* out = (float*)d_out;
  char* ws = (char*)d_ws;
  const size_t MB8 = (size_t)8 * 1024 * 1024;
  u16* Qw  = (u16*)(ws);             // [32][2048][64] bf16
  u16* Kw  = (u16*)(ws + MB8);       // [32][2048][64]
  u16* Vtw = (u16*)(ws + 2 * MB8);   // [32][64][2048]
  u16* Cw  = (u16*)(ws + 3 * MB8);   // [2][2048][1024]
  u16* Wot = (u16*)(ws + 4 * MB8);   // [1024][1024]

  k_transpose_wo<<<dim3(16, 16), 256, 0, stream>>>(Wo, Wot);
  k_proj<<<dim3(32, 32), 256, 0, stream>>>(xq, xk, xv, Wq, Wk, Wv, Qw, Kw, Vtw);
  k_attn<<<dim3(16, 32), 256, 0, stream>>>(Qw, Kw, Vtw, Cw);
  k_outproj<<<dim3(8, 32), 256, 0, stream>>>(Cw, Wot, bo, out);
}

// Round 2
// 109.673 us; speedup vs baseline: 1.3032x; 1.3032x over previous
//
#include <hip/hip_runtime.h>
#include <hip/hip_bf16.h>
#include <cstdint>

typedef unsigned short u16;
typedef __bf16 bf16x8 __attribute__((ext_vector_type(8)));
typedef u16 u16x8 __attribute__((ext_vector_type(8)));
typedef float f32x4 __attribute__((ext_vector_type(4)));

#define B_ 2
#define S_ 2048
#define H_ 16
#define HS_ 64
#define EMB_ 1024

static __device__ __forceinline__ u16 f2bf(float f) {
  unsigned int u = __float_as_uint(f);
  u += 0x7fffu + ((u >> 16) & 1u);   // RNE
  return (u16)(u >> 16);
}

static __device__ __forceinline__ f32x4 mfma16(u16x8 a, u16x8 b, f32x4 c) {
  return __builtin_amdgcn_mfma_f32_16x16x32_bf16(
      __builtin_bit_cast(bf16x8, a), __builtin_bit_cast(bf16x8, b), c, 0, 0, 0);
}

// XOR-swizzled address into a [R][64] u16 tile (128B row stride).
// byte = row*128 + colbyte, then ^= (row&7)<<4  — spreads same-column reads
// of consecutive rows across 8 distinct 16B slots (G4 fix, both-sides swizzle).
static __device__ __forceinline__ char* swzb(void* base, int row, int colbyte) {
  return (char*)base + ((row * 128 + colbyte) ^ ((row & 7) << 4));
}
static __device__ __forceinline__ u16x8* swzp(void* base, int row, int colbyte) {
  return (u16x8*)swzb(base, row, colbyte);
}

// ---------------- K0: Wo[k][n] fp32 -> Wot[n][k] bf16 ----------------
__global__ __launch_bounds__(256) void k_transpose_wo(const float* __restrict__ Wo,
                                                      u16* __restrict__ Wot) {
  __shared__ __align__(16) u16 T[64][72];
  const int kb = blockIdx.y * 64, nb = blockIdx.x * 64;
  const int r = threadIdx.x >> 2;          // 0..63
  const int c0 = (threadIdx.x & 3) << 4;   // 0,16,32,48
  const float* src = Wo + (size_t)(kb + r) * EMB_ + nb + c0;
#pragma unroll
  for (int i = 0; i < 16; i += 4) {
    float4 f = *(const float4*)(src + i);
    T[c0 + i + 0][r] = f2bf(f.x);
    T[c0 + i + 1][r] = f2bf(f.y);
    T[c0 + i + 2][r] = f2bf(f.z);
    T[c0 + i + 3][r] = f2bf(f.w);
  }
  __syncthreads();
  u16* dst = Wot + (size_t)(nb + r) * EMB_ + kb + c0;
  *(u16x8*)(dst)     = *(const u16x8*)&T[r][c0];
  *(u16x8*)(dst + 8) = *(const u16x8*)&T[r][c0 + 8];
}

// ---------------- K1: per-head projections ----------------
// Qo,Ko: [bh][s][64] bf16 row-major; Vt: [bh][e][s] bf16 (transposed)
__global__ __launch_bounds__(256) void k_proj(
    const float* __restrict__ xq, const float* __restrict__ xk, const float* __restrict__ xv,
    const float* __restrict__ Wq, const float* __restrict__ Wk, const float* __restrict__ Wv,
    u16* __restrict__ Qo, u16* __restrict__ Ko, u16* __restrict__ Vt) {
  __shared__ __align__(16) u16 X[3][64][64];
  __shared__ __align__(16) u16 WT[3][64][64];  // WT[t][e][d] = W[t][d][e]
  const int sb = blockIdx.x;   // s-block 0..31
  const int bh = blockIdx.y;   // 0..31
  const int b = bh >> 4;
  const int h = bh & 15;
  const int t = threadIdx.x;
  const int r = t >> 2;           // 0..63
  const int c0 = (t & 3) << 4;    // 0,16,32,48
  const float* xs[3] = {xq, xk, xv};
  const float* wsrc[3] = {Wq, Wk, Wv};
#pragma unroll
  for (int tn = 0; tn < 3; ++tn) {
    const float* src = xs[tn] + ((size_t)(b * S_ + sb * 64 + r)) * HS_ + c0;
#pragma unroll
    for (int i = 0; i < 16; i += 8) {
      float4 fa = *(const float4*)(src + i);
      float4 fb = *(const float4*)(src + i + 4);
      u16x8 v = {f2bf(fa.x), f2bf(fa.y), f2bf(fa.z), f2bf(fa.w),
                 f2bf(fb.x), f2bf(fb.y), f2bf(fb.z), f2bf(fb.w)};
      *swzp(&X[tn][0][0], r, (c0 + i) * 2) = v;
    }
    const float* wsp = wsrc[tn] + ((size_t)(h * HS_ + r)) * HS_ + c0;  // W[h][d=r][e]
#pragma unroll
    for (int i = 0; i < 16; i += 4) {
      float4 f = *(const float4*)(wsp + i);
      *(u16*)swzb(&WT[tn][0][0], c0 + i + 0, r * 2) = f2bf(f.x);
      *(u16*)swzb(&WT[tn][0][0], c0 + i + 1, r * 2) = f2bf(f.y);
      *(u16*)swzb(&WT[tn][0][0], c0 + i + 2, r * 2) = f2bf(f.z);
      *(u16*)swzb(&WT[tn][0][0], c0 + i + 3, r * 2) = f2bf(f.w);
    }
  }
  __syncthreads();
  const int lane = t & 63, wv = t >> 6;
  const int lq = lane & 15, lg = lane >> 4;
  // Q, K : D[s][e]
#pragma unroll
  for (int tn = 0; tn < 2; ++tn) {
    u16x8 a0 = *swzp(&X[tn][0][0], wv * 16 + lq, lg * 16);
    u16x8 a1 = *swzp(&X[tn][0][0], wv * 16 + lq, 64 + lg * 16);
    u16* outp = (tn == 0) ? Qo : Ko;
#pragma unroll
    for (int et = 0; et < 4; ++et) {
      u16x8 b0 = *swzp(&WT[tn][0][0], et * 16 + lq, lg * 16);
      u16x8 b1 = *swzp(&WT[tn][0][0], et * 16 + lq, 64 + lg * 16);
      f32x4 acc = {0.f, 0.f, 0.f, 0.f};
      acc = mfma16(a0, b0, acc);
      acc = mfma16(a1, b1, acc);
#pragma unroll
      for (int rr = 0; rr < 4; ++rr) {
        int s = sb * 64 + wv * 16 + lg * 4 + rr;
        outp[((size_t)(bh * S_ + s)) * HS_ + et * 16 + lq] = f2bf(acc[rr]);
      }
    }
  }
  // V : D[e][s] = sum_d WT[e][d] * X[s][d]  -> write transposed Vt
  u16x8 xb0 = *swzp(&X[2][0][0], wv * 16 + lq, lg * 16);
  u16x8 xb1 = *swzp(&X[2][0][0], wv * 16 + lq, 64 + lg * 16);
#pragma unroll
  for (int et = 0; et < 4; ++et) {
    u16x8 a0 = *swzp(&WT[2][0][0], et * 16 + lq, lg * 16);
    u16x8 a1 = *swzp(&WT[2][0][0], et * 16 + lq, 64 + lg * 16);
    f32x4 acc = {0.f, 0.f, 0.f, 0.f};
    acc = mfma16(a0, xb0, acc);
    acc = mfma16(a1, xb1, acc);
#pragma unroll
    for (int rr = 0; rr < 4; ++rr) {
      int e = et * 16 + lg * 4 + rr;
      int s = sb * 64 + wv * 16 + lq;
      Vt[((size_t)(bh * HS_ + e)) * S_ + s] = f2bf(acc[rr]);
    }
  }
}

// ---------------- K2: causal flash attention ----------------
// 1D grid of 512; id%8 = XCD (HW round-robin) -> each XCD owns 4 bh's so its
// concurrent K/V working set (4 x 512KB = 2MB) fits the 4MB per-XCD L2.
__global__ __launch_bounds__(256) void k_attn(
    const u16* __restrict__ Q, const u16* __restrict__ K, const u16* __restrict__ Vt,
    u16* __restrict__ Co) {
  __shared__ __align__(16) u16 Ks[64][64];      // K[kv][d], XOR-swizzled
  __shared__ __align__(16) u16 Vs[64][64];      // Vt[e][kv], XOR-swizzled
  __shared__ __align__(16) u16 Ps[4][16][72];   // per-wave P[q][kv] (padded stride)
  const int bid = blockIdx.x;
  const int xcd = bid & 7, sl = bid >> 3;       // sl 0..63
  const int bh = (xcd << 2) | (sl >> 4);        // 4 bh's per XCD
  const int pair = sl & 15;                     // qb pair 0..15
  const int b = bh >> 4, h = bh & 15;
  const int t = threadIdx.x;
  const int lane = t & 63, wv = t >> 6;
  const int lq = lane & 15, lg = lane >> 4;
  const int sr = t >> 2;           // staging row 0..63
  const int sc0 = (t & 3) << 4;    // staging col 0,16,32,48
  const float inv_scale = 0.022097086912079608f;  // 1/sqrt(2048)
  const float NEG_BIG = -1e30f;

  const u16* Kb = K + (size_t)bh * S_ * HS_;
  const u16* Vb = Vt + (size_t)bh * HS_ * S_;

  for (int halfi = 0; halfi < 2; ++halfi) {
    const int qb = (halfi == 0) ? pair : 31 - pair;
    const int q0 = qb * 64 + wv * 16;
    const u16* Qb = Q + (size_t)bh * S_ * HS_;
    u16x8 qa0 = *(const u16x8*)&Qb[(size_t)(q0 + lq) * HS_ + lg * 8];
    u16x8 qa1 = *(const u16x8*)&Qb[(size_t)(q0 + lq) * HS_ + 32 + lg * 8];
    f32x4 o[4];
#pragma unroll
    for (int et = 0; et < 4; ++et) { f32x4 z = {0.f,0.f,0.f,0.f}; o[et] = z; }
    float m[4] = {NEG_BIG, NEG_BIG, NEG_BIG, NEG_BIG};
    float ll[4] = {0.f, 0.f, 0.f, 0.f};

    // T14 reg-prefetch of K/V tiles
    u16x8 kr0, kr1, vr0, vr1;
    {
      const u16* ksrc = Kb + ((size_t)(0 * 64 + sr)) * HS_ + sc0;
      kr0 = *(const u16x8*)(ksrc);
      kr1 = *(const u16x8*)(ksrc + 8);
      const u16* vsrc = Vb + (size_t)sr * S_ + 0 * 64 + sc0;
      vr0 = *(const u16x8*)(vsrc);
      vr1 = *(const u16x8*)(vsrc + 8);
    }

    for (int j = 0; j <= qb; ++j) {
      __syncthreads();   // previous tile's consumers done
      *swzp(Ks, sr, sc0 * 2)      = kr0;
      *swzp(Ks, sr, sc0 * 2 + 16) = kr1;
      *swzp(Vs, sr, sc0 * 2)      = vr0;
      *swzp(Vs, sr, sc0 * 2 + 16) = vr1;
      __syncthreads();
      if (j < qb) {  // issue next tile's loads; they fly under the compute
        const u16* ksrc = Kb + ((size_t)((j + 1) * 64 + sr)) * HS_ + sc0;
        kr0 = *(const u16x8*)(ksrc);
        kr1 = *(const u16x8*)(ksrc + 8);
        const u16* vsrc = Vb + (size_t)sr * S_ + (j + 1) * 64 + sc0;
        vr0 = *(const u16x8*)(vsrc);
        vr1 = *(const u16x8*)(vsrc + 8);
      }
      // QK^T: D[q][kv], 4 kv-subtiles of 16
      float sv[4][4];
#pragma unroll
      for (int c = 0; c < 4; ++c) {
        u16x8 kb0 = *swzp(Ks, c * 16 + lq, lg * 16);
        u16x8 kb1 = *swzp(Ks, c * 16 + lq, 64 + lg * 16);
        f32x4 acc = {0.f, 0.f, 0.f, 0.f};
        acc = mfma16(qa0, kb0, acc);
        acc = mfma16(qa1, kb1, acc);
#pragma unroll
        for (int rr = 0; rr < 4; ++rr) sv[c][rr] = acc[rr] * inv_scale;
      }
      if (j == qb) {  // diagonal tile: causal mask
#pragma unroll
        for (int c = 0; c < 4; ++c)
#pragma unroll
          for (int rr = 0; rr < 4; ++rr) {
            int kv = c * 16 + lq;
            int qq = wv * 16 + lg * 4 + rr;
            if (kv > qq) sv[c][rr] = NEG_BIG;
          }
      }
      // online softmax (rows q = lg*4+rr; reduce over kv = 16 lanes of group)
      float scale_r[4];
#pragma unroll
      for (int rr = 0; rr < 4; ++rr) {
        float mx = fmaxf(fmaxf(sv[0][rr], sv[1][rr]), fmaxf(sv[2][rr], sv[3][rr]));
#pragma unroll
        for (int msk = 1; msk < 16; msk <<= 1) mx = fmaxf(mx, __shfl_xor(mx, msk, 64));
        float mn = fmaxf(m[rr], mx);
        float scl = __expf(m[rr] - mn);
        float ps = 0.f;
#pragma unroll
        for (int c = 0; c < 4; ++c) {
          float p = __expf(sv[c][rr] - mn);
          sv[c][rr] = p;
          ps += p;
        }
#pragma unroll
        for (int msk = 1; msk < 16; msk <<= 1) ps += __shfl_xor(ps, msk, 64);
        ll[rr] = ll[rr] * scl + ps;
        m[rr] = mn;
        scale_r[rr] = scl;
      }
      // P -> LDS (bf16), per-wave private region
#pragma unroll
      for (int c = 0; c < 4; ++c)
#pragma unroll
        for (int rr = 0; rr < 4; ++rr)
          Ps[wv][lg * 4 + rr][c * 16 + lq] = f2bf(sv[c][rr]);
      // rescale O
#pragma unroll
      for (int et = 0; et < 4; ++et)
#pragma unroll
        for (int rr = 0; rr < 4; ++rr) o[et][rr] *= scale_r[rr];
      // PV: O[q][e] += P[q][kv] * V[kv][e]
      u16x8 pa0 = *(const u16x8*)&Ps[wv][lq][lg * 8];
      u16x8 pa1 = *(const u16x8*)&Ps[wv][lq][32 + lg * 8];
#pragma unroll
      for (int et = 0; et < 4; ++et) {
        u16x8 vb0 = *swzp(Vs, et * 16 + lq, lg * 16);
        u16x8 vb1 = *swzp(Vs, et * 16 + lq, 64 + lg * 16);
        o[et] = mfma16(pa0, vb0, o[et]);
        o[et] = mfma16(pa1, vb1, o[et]);
      }
    }
    // epilogue: O /= l, write concat
#pragma unroll
    for (int rr = 0; rr < 4; ++rr) {
      float inv = 1.0f / ll[rr];
      int qg = qb * 64 + wv * 16 + lg * 4 + rr;
      u16* dst = Co + ((size_t)(b * S_ + qg)) * EMB_ + h * HS_;
#pragma unroll
      for (int et = 0; et < 4; ++et)
        dst[et * 16 + lq] = f2bf(o[et][rr] * inv);
    }
  }
}

// ---------------- K3: out = concat @ Wo + bo (fp32 out) ----------------
// 1D grid of 256; id%8 = XCD -> each XCD owns 4 mb's; B (2MB) + 4 A-panels
// (1MB) fit its L2.
__global__ __launch_bounds__(256) void k_outproj(
    const u16* __restrict__ Cc, const u16* __restrict__ Wot,
    const float* __restrict__ bo, float* __restrict__ out) {
  __shared__ __align__(16) u16 As[128][64];
  __shared__ __align__(16) u16 Bs[128][64];
  const int bid = blockIdx.x;
  const int xcd = bid & 7, sl = bid >> 3;   // sl 0..31
  const int mb = (xcd << 2) | (sl >> 3);    // 0..31
  const int nb = sl & 7;                    // 0..7
  const int t = threadIdx.x;
  const int lane = t & 63, wv = t >> 6;
  const int lq = lane & 15, lg = lane >> 4;
  const int wr = wv >> 1, wc = wv & 1;
  const int sr = t >> 1;           // 0..127
  const int sc0 = (t & 1) << 5;    // 0,32
  f32x4 acc[4][4];
#pragma unroll
  for (int mi = 0; mi < 4; ++mi)
#pragma unroll
    for (int ni = 0; ni < 4; ++ni) { f32x4 z = {0.f,0.f,0.f,0.f}; acc[mi][ni] = z; }
  const u16* abase = Cc + ((size_t)(mb * 128 + sr)) * EMB_ + sc0;
  const u16* bbase = Wot + ((size_t)(nb * 128 + sr)) * EMB_ + sc0;
  u16x8 ar[4], br[4];
#pragma unroll
  for (int q = 0; q < 4; ++q) {
    ar[q] = *(const u16x8*)(abase + q * 8);
    br[q] = *(const u16x8*)(bbase + q * 8);
  }
  for (int kt = 0; kt < 16; ++kt) {
    __syncthreads();
#pragma unroll
    for (int q = 0; q < 4; ++q) {
      *swzp(As, sr, (sc0 + q * 8) * 2) = ar[q];
      *swzp(Bs, sr, (sc0 + q * 8) * 2) = br[q];
    }
    __syncthreads();
    if (kt < 15) {
#pragma unroll
      for (int q = 0; q < 4; ++q) {
        ar[q] = *(const u16x8*)(abase + (kt + 1) * 64 + q * 8);
        br[q] = *(const u16x8*)(bbase + (kt + 1) * 64 + q * 8);
      }
    }
#pragma unroll
    for (int kf = 0; kf < 2; ++kf) {
      u16x8 af[4], bf[4];
#pragma unroll
      for (int mi = 0; mi < 4; ++mi)
        af[mi] = *swzp(As, wr * 64 + mi * 16 + lq, kf * 64 + lg * 16);
#pragma unroll
      for (int ni = 0; ni < 4; ++ni)
        bf[ni] = *swzp(Bs, wc * 64 + ni * 16 + lq, kf * 64 + lg * 16);
#pragma unroll
      for (int mi = 0; mi < 4; ++mi)
#pragma unroll
        for (int ni = 0; ni < 4; ++ni)
          acc[mi][ni] = mfma16(af[mi], bf[ni], acc[mi][ni]);
    }
  }
#pragma unroll
  for (int mi = 0; mi < 4; ++mi) {
#pragma unroll
    for (int ni = 0; ni < 4; ++ni) {
      int col = nb * 128 + wc * 64 + ni * 16 + lq;
      float bv = bo[col];
#pragma unroll
      for (int rr = 0; rr < 4; ++rr) {
        int row = mb * 128 + wr * 64 + mi * 16 + lg * 4 + rr;
        out[(size_t)row * EMB_ + col] = acc[mi][ni][rr] + bv;
      }
    }
  }
}

extern "C" void kernel_launch(void* const* d_in, const int* in_sizes, int n_in,
                              void* d_out, int out_size, void* d_ws, size_t ws_size,
                              hipStream_t stream) {
  const float* xk = (const float*)d_in[0];
  const float* xv = (const float*)d_in[1];
  const float* xq = (const float*)d_in[2];
  const float* Wk = (const float*)d_in[3];
  const float* Wv = (const float*)d_in[4];
  const float* Wq = (const float*)d_in[5];
  const float* Wo = (const float*)d_in[6];
  const float* bo = (const float*)d_in[7];
  float* out = (float*)d_out;
  char* ws = (char*)d_ws;
  const size_t MB8 = (size_t)8 * 1024 * 1024;
  u16* Qw  = (u16*)(ws);             // [32][2048][64] bf16
  u16* Kw  = (u16*)(ws + MB8);       // [32][2048][64]
  u16* Vtw = (u16*)(ws + 2 * MB8);   // [32][64][2048]
  u16* Cw  = (u16*)(ws + 3 * MB8);   // [2][2048][1024]
  u16* Wot = (u16*)(ws + 4 * MB8);   // [1024][1024]

  k_transpose_wo<<<dim3(16, 16), 256, 0, stream>>>(Wo, Wot);
  k_proj<<<dim3(32, 32), 256, 0, stream>>>(xq, xk, xv, Wq, Wk, Wv, Qw, Kw, Vtw);
  k_attn<<<512, 256, 0, stream>>>(Qw, Kw, Vtw, Cw);
  k_outproj<<<256, 256, 0, stream>>>(Cw, Wot, bo, out);
}

// Round 3
// 92.642 us; speedup vs baseline: 1.5428x; 1.1838x over previous
//
#include <hip/hip_runtime.h>
#include <hip/hip_bf16.h>
#include <cstdint>

typedef unsigned short u16;
typedef __bf16 bf16x8 __attribute__((ext_vector_type(8)));
typedef u16 u16x8 __attribute__((ext_vector_type(8)));
typedef unsigned u32x4 __attribute__((ext_vector_type(4)));
typedef float f32x4 __attribute__((ext_vector_type(4)));
typedef float f32x16 __attribute__((ext_vector_type(16)));

#define B_ 2
#define S_ 2048
#define H_ 16
#define HS_ 64
#define EMB_ 1024
#define QSCALE 0.022097086912079608f  /* 1/sqrt(2048), folded into Q */

static __device__ __forceinline__ u16 f2bf(float f) {
  unsigned int u = __float_as_uint(f);
  u += 0x7fffu + ((u >> 16) & 1u);   // RNE
  return (u16)(u >> 16);
}

static __device__ __forceinline__ f32x4 mfma16(u16x8 a, u16x8 b, f32x4 c) {
  return __builtin_amdgcn_mfma_f32_16x16x32_bf16(
      __builtin_bit_cast(bf16x8, a), __builtin_bit_cast(bf16x8, b), c, 0, 0, 0);
}
static __device__ __forceinline__ f32x16 mfma32(u16x8 a, u16x8 b, f32x16 c) {
  return __builtin_amdgcn_mfma_f32_32x32x16_bf16(
      __builtin_bit_cast(bf16x8, a), __builtin_bit_cast(bf16x8, b), c, 0, 0, 0);
}

// XOR-swizzled address into a [R][64] u16 tile (128B row stride).
static __device__ __forceinline__ char* swzb(void* base, int row, int colbyte) {
  return (char*)base + ((row * 128 + colbyte) ^ ((row & 7) << 4));
}
static __device__ __forceinline__ u16x8* swzp(void* base, int row, int colbyte) {
  return (u16x8*)swzb(base, row, colbyte);
}

// cvt_pk two f32 pairs to packed bf16 words, then permlane32_swap:
// x' = {a-word lanes0-31, b-word lanes0-31}, y' = {a-word lanes32-63, b-word lanes32-63}
static __device__ __forceinline__ void pk_swap(float a0, float a1, float b0, float b1,
                                               unsigned& x, unsigned& y) {
  unsigned A, Bv;
  asm("v_cvt_pk_bf16_f32 %0, %1, %2" : "=v"(A) : "v"(a0), "v"(a1));
  asm("v_cvt_pk_bf16_f32 %0, %1, %2" : "=v"(Bv) : "v"(b0), "v"(b1));
  asm("v_permlane32_swap_b32 %0, %1" : "+v"(A), "+v"(Bv));
  x = A; y = Bv;
}

// ---------------- K0: Wo[k][n] fp32 -> Wot[n][k] bf16 ----------------
__global__ __launch_bounds__(256) void k_transpose_wo(const float* __restrict__ Wo,
                                                      u16* __restrict__ Wot) {
  __shared__ __align__(16) u16 T[64][72];
  const int kb = blockIdx.y * 64, nb = blockIdx.x * 64;
  const int r = threadIdx.x >> 2;
  const int c0 = (threadIdx.x & 3) << 4;
  const float* src = Wo + (size_t)(kb + r) * EMB_ + nb + c0;
#pragma unroll
  for (int i = 0; i < 16; i += 4) {
    float4 f = *(const float4*)(src + i);
    T[c0 + i + 0][r] = f2bf(f.x);
    T[c0 + i + 1][r] = f2bf(f.y);
    T[c0 + i + 2][r] = f2bf(f.z);
    T[c0 + i + 3][r] = f2bf(f.w);
  }
  __syncthreads();
  u16* dst = Wot + (size_t)(nb + r) * EMB_ + kb + c0;
  *(u16x8*)(dst)     = *(const u16x8*)&T[r][c0];
  *(u16x8*)(dst + 8) = *(const u16x8*)&T[r][c0 + 8];
}

// ---------------- K1: per-head projections ----------------
// Qo (pre-scaled by QSCALE), Ko: [bh][s][64]; Vt: [bh][e][s] (transposed)
__global__ __launch_bounds__(256) void k_proj(
    const float* __restrict__ xq, const float* __restrict__ xk, const float* __restrict__ xv,
    const float* __restrict__ Wq, const float* __restrict__ Wk, const float* __restrict__ Wv,
    u16* __restrict__ Qo, u16* __restrict__ Ko, u16* __restrict__ Vt) {
  __shared__ __align__(16) u16 X[3][64][64];
  __shared__ __align__(16) u16 WT[3][64][64];
  const int sb = blockIdx.x;
  const int bh = blockIdx.y;
  const int b = bh >> 4;
  const int h = bh & 15;
  const int t = threadIdx.x;
  const int r = t >> 2;
  const int c0 = (t & 3) << 4;
  const float* xs[3] = {xq, xk, xv};
  const float* wsrc[3] = {Wq, Wk, Wv};
#pragma unroll
  for (int tn = 0; tn < 3; ++tn) {
    const float* src = xs[tn] + ((size_t)(b * S_ + sb * 64 + r)) * HS_ + c0;
#pragma unroll
    for (int i = 0; i < 16; i += 8) {
      float4 fa = *(const float4*)(src + i);
      float4 fb = *(const float4*)(src + i + 4);
      u16x8 v = {f2bf(fa.x), f2bf(fa.y), f2bf(fa.z), f2bf(fa.w),
                 f2bf(fb.x), f2bf(fb.y), f2bf(fb.z), f2bf(fb.w)};
      *swzp(&X[tn][0][0], r, (c0 + i) * 2) = v;
    }
    const float* wsp = wsrc[tn] + ((size_t)(h * HS_ + r)) * HS_ + c0;
#pragma unroll
    for (int i = 0; i < 16; i += 4) {
      float4 f = *(const float4*)(wsp + i);
      *(u16*)swzb(&WT[tn][0][0], c0 + i + 0, r * 2) = f2bf(f.x);
      *(u16*)swzb(&WT[tn][0][0], c0 + i + 1, r * 2) = f2bf(f.y);
      *(u16*)swzb(&WT[tn][0][0], c0 + i + 2, r * 2) = f2bf(f.z);
      *(u16*)swzb(&WT[tn][0][0], c0 + i + 3, r * 2) = f2bf(f.w);
    }
  }
  __syncthreads();
  const int lane = t & 63, wv = t >> 6;
  const int lq = lane & 15, lg = lane >> 4;
#pragma unroll
  for (int tn = 0; tn < 2; ++tn) {
    u16x8 a0 = *swzp(&X[tn][0][0], wv * 16 + lq, lg * 16);
    u16x8 a1 = *swzp(&X[tn][0][0], wv * 16 + lq, 64 + lg * 16);
    u16* outp = (tn == 0) ? Qo : Ko;
    const float osc = (tn == 0) ? QSCALE : 1.0f;
#pragma unroll
    for (int et = 0; et < 4; ++et) {
      u16x8 b0 = *swzp(&WT[tn][0][0], et * 16 + lq, lg * 16);
      u16x8 b1 = *swzp(&WT[tn][0][0], et * 16 + lq, 64 + lg * 16);
      f32x4 acc = {0.f, 0.f, 0.f, 0.f};
      acc = mfma16(a0, b0, acc);
      acc = mfma16(a1, b1, acc);
#pragma unroll
      for (int rr = 0; rr < 4; ++rr) {
        int s = sb * 64 + wv * 16 + lg * 4 + rr;
        outp[((size_t)(bh * S_ + s)) * HS_ + et * 16 + lq] = f2bf(acc[rr] * osc);
      }
    }
  }
  u16x8 xb0 = *swzp(&X[2][0][0], wv * 16 + lq, lg * 16);
  u16x8 xb1 = *swzp(&X[2][0][0], wv * 16 + lq, 64 + lg * 16);
#pragma unroll
  for (int et = 0; et < 4; ++et) {
    u16x8 a0 = *swzp(&WT[2][0][0], et * 16 + lq, lg * 16);
    u16x8 a1 = *swzp(&WT[2][0][0], et * 16 + lq, 64 + lg * 16);
    f32x4 acc = {0.f, 0.f, 0.f, 0.f};
    acc = mfma16(a0, xb0, acc);
    acc = mfma16(a1, xb1, acc);
#pragma unroll
    for (int rr = 0; rr < 4; ++rr) {
      int e = et * 16 + lg * 4 + rr;
      int s = sb * 64 + wv * 16 + lq;
      Vt[((size_t)(bh * HS_ + e)) * S_ + s] = f2bf(acc[rr]);
    }
  }
}

// ---------------- K2: causal flash attention, swapped-QK 32x32 ----------------
// 2 waves/block, each wave owns 32 q-rows; block = one 64-row q-tile.
// Grid 1024: xcd = bid&7 (4 bh per XCD for L2 locality), qb descending (load balance).
__global__ __launch_bounds__(128) void k_attn(
    const u16* __restrict__ Q, const u16* __restrict__ K, const u16* __restrict__ Vt,
    u16* __restrict__ Co) {
  __shared__ __align__(16) u16 Ks[64][64];   // K[kv][d], swizzled; reused as O-scratch
  __shared__ __align__(16) u16 Vs[64][64];   // Vt[e][kv], swizzled
  const int bid = blockIdx.x;
  const int xcd = bid & 7, idx = bid >> 3;
  const int bh = (xcd << 2) | (idx & 3);
  const int qb = 31 - (idx >> 2);
  const int b = bh >> 4, h = bh & 15;
  const int t = threadIdx.x;
  const int w = t >> 6, l = t & 63;
  const int lq = l & 31, hi = l >> 5;
  const int qg = qb * 64 + w * 32 + lq;      // this lane's q row
  const int sr = t >> 1, sc0 = (t & 1) << 5; // staging: 2 threads/row, 32 elems each
  const int jmax = qb;
  const float NEG = -3.0e38f;

  const u16* Qb = Q + (size_t)bh * S_ * HS_;
  const u16* Kb = K + (size_t)bh * S_ * HS_;
  const u16* Vb = Vt + (size_t)bh * HS_ * S_;

  // Q fragments (B-operand of swapped QK): Q[qg][tt*16 + hi*8 + j]
  u16x8 qf0 = *(const u16x8*)&Qb[(size_t)qg * HS_ + 0 * 16 + hi * 8];
  u16x8 qf1 = *(const u16x8*)&Qb[(size_t)qg * HS_ + 1 * 16 + hi * 8];
  u16x8 qf2 = *(const u16x8*)&Qb[(size_t)qg * HS_ + 2 * 16 + hi * 8];
  u16x8 qf3 = *(const u16x8*)&Qb[(size_t)qg * HS_ + 3 * 16 + hi * 8];

  f32x16 o0, o1;  // O^T[e][q]: o0 -> e 0..31, o1 -> e 32..63 (rows), col q = lq
#pragma unroll
  for (int r = 0; r < 16; ++r) { o0[r] = 0.f; o1[r] = 0.f; }
  float m = NEG, ll = 0.f;

  // T14 reg-prefetch of tile 0
  u16x8 kp[4], vp[4];
#pragma unroll
  for (int q8 = 0; q8 < 4; ++q8) {
    kp[q8] = *(const u16x8*)&Kb[(size_t)sr * HS_ + sc0 + q8 * 8];
    vp[q8] = *(const u16x8*)&Vb[(size_t)sr * S_ + sc0 + q8 * 8];
  }

  for (int j = 0; j <= jmax; ++j) {
    __syncthreads();
#pragma unroll
    for (int q8 = 0; q8 < 4; ++q8) {
      *swzp(Ks, sr, (sc0 + q8 * 8) * 2) = kp[q8];
      *swzp(Vs, sr, (sc0 + q8 * 8) * 2) = vp[q8];
    }
    __syncthreads();
    if (j < jmax) {
#pragma unroll
      for (int q8 = 0; q8 < 4; ++q8) {
        kp[q8] = *(const u16x8*)&Kb[(size_t)((j + 1) * 64 + sr) * HS_ + sc0 + q8 * 8];
        vp[q8] = *(const u16x8*)&Vb[(size_t)sr * S_ + (j + 1) * 64 + sc0 + q8 * 8];
      }
    }
    // warp0's upper kv-subtile is fully masked on the diagonal tile -> skip
    const bool n1 = !(j == jmax && w == 0);

    // QK^T swapped: S^T[kv][q] += K[kv][d] * Q[q][d]
    f32x16 s0, s1;
#pragma unroll
    for (int r = 0; r < 16; ++r) { s0[r] = 0.f; s1[r] = 0.f; }
    __builtin_amdgcn_s_setprio(1);
    {
      u16x8 kf;
      kf = *swzp(Ks, lq, 0 * 32 + hi * 16); s0 = mfma32(kf, qf0, s0);
      kf = *swzp(Ks, lq, 1 * 32 + hi * 16); s0 = mfma32(kf, qf1, s0);
      kf = *swzp(Ks, lq, 2 * 32 + hi * 16); s0 = mfma32(kf, qf2, s0);
      kf = *swzp(Ks, lq, 3 * 32 + hi * 16); s0 = mfma32(kf, qf3, s0);
    }
    if (n1) {
      u16x8 kf;
      kf = *swzp(Ks, 32 + lq, 0 * 32 + hi * 16); s1 = mfma32(kf, qf0, s1);
      kf = *swzp(Ks, 32 + lq, 1 * 32 + hi * 16); s1 = mfma32(kf, qf1, s1);
      kf = *swzp(Ks, 32 + lq, 2 * 32 + hi * 16); s1 = mfma32(kf, qf2, s1);
      kf = *swzp(Ks, 32 + lq, 3 * 32 + hi * 16); s1 = mfma32(kf, qf3, s1);
    }
    __builtin_amdgcn_s_setprio(0);

    if (j == jmax) {  // causal mask on diagonal tile; kv row = (r&3)+8*(r>>2)+4*hi
#pragma unroll
      for (int r = 0; r < 16; ++r) {
        int kv = j * 64 + (r & 3) + 8 * (r >> 2) + 4 * hi;
        if (kv > qg) s0[r] = NEG;
        if (n1 && (kv + 32 > qg)) s1[r] = NEG;
      }
    }
    // in-register online softmax (lane owns one q-row half; partner = lane^32)
    float pm = NEG;
#pragma unroll
    for (int r = 0; r < 16; ++r) pm = fmaxf(pm, s0[r]);
    if (n1) {
#pragma unroll
      for (int r = 0; r < 16; ++r) pm = fmaxf(pm, s1[r]);
    }
    pm = fmaxf(pm, __shfl_xor(pm, 32));
    if (__any(pm > m + 8.0f)) {   // T13 defer-max, THR=8 (P bounded by e^8)
      float mn = fmaxf(m, pm);
      float scl = __expf(m - mn);
#pragma unroll
      for (int r = 0; r < 16; ++r) { o0[r] *= scl; o1[r] *= scl; }
      ll *= scl;
      m = mn;
    }
    float ps = 0.f;
#pragma unroll
    for (int r = 0; r < 16; ++r) { s0[r] = __expf(s0[r] - m); ps += s0[r]; }
    if (n1) {
#pragma unroll
      for (int r = 0; r < 16; ++r) { s1[r] = __expf(s1[r] - m); ps += s1[r]; }
    }
    ps += __shfl_xor(ps, 32);
    ll += ps;

    // T12: pack P rows into PV B-fragments via cvt_pk + permlane32_swap
    u16x8 pf0, pf1, pf2, pf3;
    {
      unsigned w0, w1, w2, w3;
      pk_swap(s0[0], s0[1], s0[4], s0[5], w0, w2);
      pk_swap(s0[2], s0[3], s0[6], s0[7], w1, w3);
      pf0 = __builtin_bit_cast(u16x8, (u32x4){w0, w1, w2, w3});
      pk_swap(s0[8], s0[9], s0[12], s0[13], w0, w2);
      pk_swap(s0[10], s0[11], s0[14], s0[15], w1, w3);
      pf1 = __builtin_bit_cast(u16x8, (u32x4){w0, w1, w2, w3});
      if (n1) {
        pk_swap(s1[0], s1[1], s1[4], s1[5], w0, w2);
        pk_swap(s1[2], s1[3], s1[6], s1[7], w1, w3);
        pf2 = __builtin_bit_cast(u16x8, (u32x4){w0, w1, w2, w3});
        pk_swap(s1[8], s1[9], s1[12], s1[13], w0, w2);
        pk_swap(s1[10], s1[11], s1[14], s1[15], w1, w3);
        pf3 = __builtin_bit_cast(u16x8, (u32x4){w0, w1, w2, w3});
      }
    }
    // PV: O^T[e][q] += Vt[e][kv] * P[kv][q]
    __builtin_amdgcn_s_setprio(1);
    {
      u16x8 vf;
      vf = *swzp(Vs, lq,      0 * 32 + hi * 16); o0 = mfma32(vf, pf0, o0);
      vf = *swzp(Vs, 32 + lq, 0 * 32 + hi * 16); o1 = mfma32(vf, pf0, o1);
      vf = *swzp(Vs, lq,      1 * 32 + hi * 16); o0 = mfma32(vf, pf1, o0);
      vf = *swzp(Vs, 32 + lq, 1 * 32 + hi * 16); o1 = mfma32(vf, pf1, o1);
      if (n1) {
        vf = *swzp(Vs, lq,      2 * 32 + hi * 16); o0 = mfma32(vf, pf2, o0);
        vf = *swzp(Vs, 32 + lq, 2 * 32 + hi * 16); o1 = mfma32(vf, pf2, o1);
        vf = *swzp(Vs, lq,      3 * 32 + hi * 16); o0 = mfma32(vf, pf3, o0);
        vf = *swzp(Vs, 32 + lq, 3 * 32 + hi * 16); o1 = mfma32(vf, pf3, o1);
      }
    }
    __builtin_amdgcn_s_setprio(0);
  }

  // epilogue: normalize, transpose through LDS (warp-private region in Ks), store
  __syncthreads();   // all QK/PV reads of Ks/Vs done block-wide
  float inv = 1.0f / ll;
  char* Osw = (char*)Ks + w * 4096;  // 32 rows x 128B per warp
#pragma unroll
  for (int r = 0; r < 16; ++r) {
    int drow = (r & 3) + 8 * (r >> 2) + 4 * hi;
    *(u16*)swzb(Osw, lq, (drow) * 2)      = f2bf(o0[r] * inv);
    *(u16*)swzb(Osw, lq, (32 + drow) * 2) = f2bf(o1[r] * inv);
  }
  __syncthreads();
  u16* dst = Co + ((size_t)(b * S_ + qg)) * EMB_ + h * HS_ + hi * 32;
#pragma unroll
  for (int k = 0; k < 4; ++k) {
    u16x8 vv = *swzp(Osw, lq, (hi * 32 + k * 8) * 2);
    *(u16x8*)(dst + k * 8) = vv;
  }
}

// ---------------- K3: out = concat @ Wo + bo (fp32 out) ----------------
__global__ __launch_bounds__(256) void k_outproj(
    const u16* __restrict__ Cc, const u16* __restrict__ Wot,
    const float* __restrict__ bo, float* __restrict__ out) {
  __shared__ __align__(16) u16 As[128][64];
  __shared__ __align__(16) u16 Bs[128][64];
  const int bid = blockIdx.x;
  const int xcd = bid & 7, sl = bid >> 3;
  const int mb = (xcd << 2) | (sl >> 3);
  const int nb = sl & 7;
  const int t = threadIdx.x;
  const int lane = t & 63, wv = t >> 6;
  const int lq = lane & 15, lg = lane >> 4;
  const int wr = wv >> 1, wc = wv & 1;
  const int sr = t >> 1;
  const int sc0 = (t & 1) << 5;
  f32x4 acc[4][4];
#pragma unroll
  for (int mi = 0; mi < 4; ++mi)
#pragma unroll
    for (int ni = 0; ni < 4; ++ni) { f32x4 z = {0.f,0.f,0.f,0.f}; acc[mi][ni] = z; }
  const u16* abase = Cc + ((size_t)(mb * 128 + sr)) * EMB_ + sc0;
  const u16* bbase = Wot + ((size_t)(nb * 128 + sr)) * EMB_ + sc0;
  u16x8 ar[4], br[4];
#pragma unroll
  for (int q = 0; q < 4; ++q) {
    ar[q] = *(const u16x8*)(abase + q * 8);
    br[q] = *(const u16x8*)(bbase + q * 8);
  }
  for (int kt = 0; kt < 16; ++kt) {
    __syncthreads();
#pragma unroll
    for (int q = 0; q < 4; ++q) {
      *swzp(As, sr, (sc0 + q * 8) * 2) = ar[q];
      *swzp(Bs, sr, (sc0 + q * 8) * 2) = br[q];
    }
    __syncthreads();
    if (kt < 15) {
#pragma unroll
      for (int q = 0; q < 4; ++q) {
        ar[q] = *(const u16x8*)(abase + (kt + 1) * 64 + q * 8);
        br[q] = *(const u16x8*)(bbase + (kt + 1) * 64 + q * 8);
      }
    }
#pragma unroll
    for (int kf = 0; kf < 2; ++kf) {
      u16x8 af[4], bf[4];
#pragma unroll
      for (int mi = 0; mi < 4; ++mi)
        af[mi] = *swzp(As, wr * 64 + mi * 16 + lq, kf * 64 + lg * 16);
#pragma unroll
      for (int ni = 0; ni < 4; ++ni)
        bf[ni] = *swzp(Bs, wc * 64 + ni * 16 + lq, kf * 64 + lg * 16);
#pragma unroll
      for (int mi = 0; mi < 4; ++mi)
#pragma unroll
        for (int ni = 0; ni < 4; ++ni)
          acc[mi][ni] = mfma16(af[mi], bf[ni], acc[mi][ni]);
    }
  }
#pragma unroll
  for (int mi = 0; mi < 4; ++mi) {
#pragma unroll
    for (int ni = 0; ni < 4; ++ni) {
      int col = nb * 128 + wc * 64 + ni * 16 + lq;
      float bv = bo[col];
#pragma unroll
      for (int rr = 0; rr < 4; ++rr) {
        int row = mb * 128 + wr * 64 + mi * 16 + lg * 4 + rr;
        out[(size_t)row * EMB_ + col] = acc[mi][ni][rr] + bv;
      }
    }
  }
}

extern "C" void kernel_launch(void* const* d_in, const int* in_sizes, int n_in,
                              void* d_out, int out_size, void* d_ws, size_t ws_size,
                              hipStream_t stream) {
  const float* xk = (const float*)d_in[0];
  const float* xv = (const float*)d_in[1];
  const float* xq = (const float*)d_in[2];
  const float* Wk = (const float*)d_in[3];
  const float* Wv = (const float*)d_in[4];
  const float* Wq = (const float*)d_in[5];
  const float* Wo = (const float*)d_in[6];
  const float* bo = (const float*)d_in[7];
  float* out = (float*)d_out;
  char* ws = (char*)d_ws;
  const size_t MB8 = (size_t)8 * 1024 * 1024;
  u16* Qw  = (u16*)(ws);             // [32][2048][64] bf16 (pre-scaled)
  u16* Kw  = (u16*)(ws + MB8);       // [32][2048][64]
  u16* Vtw = (u16*)(ws + 2 * MB8);   // [32][64][2048]
  u16* Cw  = (u16*)(ws + 3 * MB8);   // [2][2048][1024]
  u16* Wot = (u16*)(ws + 4 * MB8);   // [1024][1024]

  k_transpose_wo<<<dim3(16, 16), 256, 0, stream>>>(Wo, Wot);
  k_proj<<<dim3(32, 32), 256, 0, stream>>>(xq, xk, xv, Wq, Wk, Wv, Qw, Kw, Vtw);
  k_attn<<<1024, 128, 0, stream>>>(Qw, Kw, Vtw, Cw);
  k_outproj<<<256, 256, 0, stream>>>(Cw, Wot, bo, out);
}